// Round 1
// baseline (601.390 us; speedup 1.0000x reference)
//
#include <hip/hip_runtime.h>
#include <math.h>

#define BB 4
#define CC 19
#define HH 512
#define WW 1024
#define NPIX (HH * WW)          // 524288 = 2^19
#define NB 640                  // histogram bins over max_prob in [0,1]
#define CONF_BIN 576            // 0.9 * 640 exactly -> bin>=576 <=> p>=0.9
#define FRACTION_F 0.66f

// ws layout: int hist[BB*CC*NB]; then float sumnll[BB*CC*NB]
#define HIST_ELEMS (BB * CC * NB)

__global__ __launch_bounds__(256) void st_pass1(const float* __restrict__ pred,
                                                int* __restrict__ hist,
                                                float* __restrict__ sumnll) {
    int t = blockIdx.x * 256 + threadIdx.x;     // one thread -> 4 consecutive pixels
    int pix = t << 2;                           // global pixel index
    int b = pix >> 19;                          // / NPIX
    int p0 = pix & (NPIX - 1);
    const float* base = pred + (size_t)b * CC * NPIX + p0;

    float4 v0 = *(const float4*)base;           // channel 0
    float m[4] = {v0.x, v0.y, v0.z, v0.w};
    float s[4] = {1.f, 1.f, 1.f, 1.f};
    int arg[4] = {0, 0, 0, 0};

    for (int c = 1; c < CC; ++c) {
        float4 v = *(const float4*)(base + (size_t)c * NPIX);
        float vv[4] = {v.x, v.y, v.z, v.w};
        #pragma unroll
        for (int j = 0; j < 4; ++j) {
            float x = vv[j];
            float nm = fmaxf(m[j], x);
            // online logsumexp: both exps' args are <= 0
            s[j] = s[j] * __expf(m[j] - nm) + __expf(x - nm);
            arg[j] = (x > m[j]) ? c : arg[j];   // strict > keeps first max (jnp.argmax)
            m[j] = nm;
        }
    }

    #pragma unroll
    for (int j = 0; j < 4; ++j) {
        float prob = 1.f / s[j];                // max softmax prob
        float nll  = __logf(s[j]);              // -log(max_prob)
        int bin = (int)(prob * (float)NB);
        bin = min(bin, NB - 1);
        int idx = (b * CC + arg[j]) * NB + bin;
        atomicAdd(&hist[idx], 1);
        atomicAdd(&sumnll[idx], nll);
    }
}

__global__ __launch_bounds__(128) void st_pass2(const int* __restrict__ hist,
                                                const float* __restrict__ sumnll,
                                                float* __restrict__ out) {
    __shared__ float red[128];
    int t = threadIdx.x;
    float sel = 0.f;
    if (t < BB * CC) {
        const int* h = hist + t * NB;
        const float* sn = sumnll + t * NB;
        int count = 0;
        for (int i = 0; i < NB; ++i) count += h[i];
        float conf = 0.f;                       // sum of nll where p >= 0.9
        for (int i = CONF_BIN; i < NB; ++i) conf += sn[i];
        int k = (int)floorf((float)count * FRACTION_F);  // match jnp float32 math
        if (k == 0) {
            sel = conf;                         // rank set empty -> only conf mask
        } else {
            int cum = 0;                        // count in bins strictly above boundary
            float csum = 0.f;                   // nll sum in those bins
            int bin = NB - 1;
            int hh = 0;
            for (; bin >= 0; --bin) {
                hh = h[bin];
                if (cum + hh >= k) break;       // rank k-1 lies in this bin
                cum += hh;
                csum += sn[bin];
            }
            if (bin < 0) {
                sel = csum;                     // can't happen (k < count), safety
            } else if (bin >= CONF_BIN) {
                // cutoff value t >= 0.9 -> union mask == {p > 0.9}
                sel = conf;
            } else {
                // take (k - cum) pixels from boundary bin at its average nll
                float avg = sn[bin] / (float)max(hh, 1);
                sel = csum + (float)(k - cum) * avg;
            }
        }
    }
    red[t] = sel;
    __syncthreads();
    for (int off = 64; off > 0; off >>= 1) {
        if (t < off) red[t] += red[t + off];
        __syncthreads();
    }
    if (t == 0) out[0] = red[0] * (1.0f / (float)(BB * (size_t)NPIX));  // mean over ALL pixels, LAMBDA=1
}

extern "C" void kernel_launch(void* const* d_in, const int* in_sizes, int n_in,
                              void* d_out, int out_size, void* d_ws, size_t ws_size,
                              hipStream_t stream) {
    const float* pred = (const float*)d_in[0];
    float* out = (float*)d_out;
    int* hist = (int*)d_ws;
    float* sumnll = (float*)((char*)d_ws + (size_t)HIST_ELEMS * sizeof(int));

    // zero the histograms every call (ws is poisoned once, never re-poisoned)
    hipMemsetAsync(d_ws, 0, (size_t)HIST_ELEMS * (sizeof(int) + sizeof(float)), stream);

    int total_threads = (BB * NPIX) / 4;        // 524288 threads
    int blocks = total_threads / 256;           // 2048
    st_pass1<<<blocks, 256, 0, stream>>>(pred, hist, sumnll);
    st_pass2<<<1, 128, 0, stream>>>(hist, sumnll, out);
}

// Round 2
// 51.799 us; speedup vs baseline: 11.6101x; 11.6101x over previous
//
#include <hip/hip_runtime.h>
#include <math.h>

#define BB 4
#define CC 19
#define HH 512
#define WW 1024
#define NPIX (HH * WW)          // 524288 = 2^19
#define NB 160                  // histogram bins over max_prob in [0,1]
#define CONF_BIN 144            // 0.9 * 160 exactly -> bin>=144 <=> p>=0.9
#define FRACTION_F 0.66f
#define ROW (CC * NB)           // 3040 bins per image-block histogram

#define NBLK1 512
#define BLKS_PER_IMG (NBLK1 / BB)        // 128
#define PIX_PER_BLK (NPIX / BLKS_PER_IMG) // 4096
#define ITERS (PIX_PER_BLK / (256 * 4))   // 4

// ws layout:
//   int   cntPart[NBLK1][ROW]   (6.23 MB)
//   float snlPart[NBLK1][ROW]   (6.23 MB)
//   float selbuf[BB*CC]         (304 B)

__global__ __launch_bounds__(256, 2) void st_pass1(const float* __restrict__ pred,
                                                   int* __restrict__ cntPart,
                                                   float* __restrict__ snlPart) {
    __shared__ int   hcnt[ROW];
    __shared__ float hsnl[ROW];
    int tid = threadIdx.x;
    for (int i = tid; i < ROW; i += 256) { hcnt[i] = 0; hsnl[i] = 0.f; }
    __syncthreads();

    int blk = blockIdx.x;
    int b   = blk >> 7;                  // / BLKS_PER_IMG
    int seg = blk & (BLKS_PER_IMG - 1);
    const float* base = pred + (size_t)b * CC * NPIX + (size_t)seg * PIX_PER_BLK;

    for (int it = 0; it < ITERS; ++it) {
        const float* bp = base + it * 1024 + tid * 4;
        // issue all 19 channel loads first -> 19 outstanding per thread
        float4 v[CC];
        #pragma unroll
        for (int c = 0; c < CC; ++c)
            v[c] = *(const float4*)(bp + (size_t)c * NPIX);

        #pragma unroll
        for (int j = 0; j < 4; ++j) {
            float m = ((const float*)&v[0])[j];
            float s = 1.f;
            int   arg = 0;
            #pragma unroll
            for (int c = 1; c < CC; ++c) {
                float x  = ((const float*)&v[c])[j];
                float nm = fmaxf(m, x);
                s = s * __expf(m - nm) + __expf(x - nm);
                arg = (x > m) ? c : arg;     // strict > keeps first max (jnp.argmax)
                m = nm;
            }
            float prob = 1.f / s;            // max softmax prob
            float nll  = __logf(s);          // -log(max_prob)
            int bin = (int)(prob * (float)NB);
            bin = min(bin, NB - 1);
            int idx = arg * NB + bin;
            atomicAdd(&hcnt[idx], 1);        // LDS atomics: CU-local, cheap
            atomicAdd(&hsnl[idx], nll);
        }
    }
    __syncthreads();

    // flush private slice with plain coalesced stores (no global atomics)
    int*   cp = cntPart + (size_t)blk * ROW;
    float* sp = snlPart + (size_t)blk * ROW;
    for (int i = tid; i < ROW; i += 256) { cp[i] = hcnt[i]; sp[i] = hsnl[i]; }
}

__global__ __launch_bounds__(256) void st_pass2(const int* __restrict__ cntPart,
                                                const float* __restrict__ snlPart,
                                                float* __restrict__ selbuf) {
    __shared__ int   scnt[NB];
    __shared__ float ssnl[NB];
    int row = blockIdx.x;                    // 0..75  (b*CC + c)
    int b = row / CC;
    int c = row % CC;
    int tid = threadIdx.x;

    if (tid < NB) {
        int cs = 0; float ss = 0.f;
        size_t off = (size_t)(b * BLKS_PER_IMG) * ROW + (size_t)c * NB + tid;
        const int*   cp = cntPart + off;
        const float* sp = snlPart + off;
        for (int p = 0; p < BLKS_PER_IMG; ++p) {
            cs += cp[(size_t)p * ROW];
            ss += sp[(size_t)p * ROW];
        }
        scnt[tid] = cs;
        ssnl[tid] = ss;
    }
    __syncthreads();

    if (tid == 0) {
        int count = 0;
        for (int i = 0; i < NB; ++i) count += scnt[i];
        float conf = 0.f;                    // sum of nll where p >= 0.9
        for (int i = CONF_BIN; i < NB; ++i) conf += ssnl[i];
        int k = (int)floorf((float)count * FRACTION_F);  // match jnp f32 math
        float sel;
        if (k == 0) {
            sel = conf;
        } else {
            int cum = 0;                     // count in bins strictly above boundary
            float csum = 0.f;
            int bin = NB - 1;
            int hh = 0;
            for (; bin >= 0; --bin) {
                hh = scnt[bin];
                if (cum + hh >= k) break;    // rank k-1 lies in this bin
                cum += hh;
                csum += ssnl[bin];
            }
            if (bin < 0) {
                sel = csum;                  // safety (k < count always)
            } else if (bin >= CONF_BIN) {
                sel = conf;                  // cutoff >= 0.9 -> union == {p>0.9}
            } else {
                float avg = ssnl[bin] / (float)max(hh, 1);
                sel = csum + (float)(k - cum) * avg;
            }
        }
        selbuf[row] = sel;
    }
}

__global__ __launch_bounds__(128) void st_pass3(const float* __restrict__ selbuf,
                                                float* __restrict__ out) {
    __shared__ float red[128];
    int t = threadIdx.x;
    red[t] = (t < BB * CC) ? selbuf[t] : 0.f;
    __syncthreads();
    for (int off = 64; off > 0; off >>= 1) {
        if (t < off) red[t] += red[t + off];
        __syncthreads();
    }
    if (t == 0) out[0] = red[0] * (1.0f / (float)(BB * (size_t)NPIX));
}

extern "C" void kernel_launch(void* const* d_in, const int* in_sizes, int n_in,
                              void* d_out, int out_size, void* d_ws, size_t ws_size,
                              hipStream_t stream) {
    const float* pred = (const float*)d_in[0];
    float* out = (float*)d_out;

    int*   cntPart = (int*)d_ws;
    float* snlPart = (float*)((char*)d_ws + (size_t)NBLK1 * ROW * sizeof(int));
    float* selbuf  = (float*)((char*)d_ws + (size_t)NBLK1 * ROW * (sizeof(int) + sizeof(float)));

    st_pass1<<<NBLK1, 256, 0, stream>>>(pred, cntPart, snlPart);
    st_pass2<<<BB * CC, 256, 0, stream>>>(cntPart, snlPart, selbuf);
    st_pass3<<<1, 128, 0, stream>>>(selbuf, out);
}